// Round 1
// baseline (655.802 us; speedup 1.0000x reference)
//
#include <hip/hip_runtime.h>

typedef float  f32x4  __attribute__((ext_vector_type(4)));
typedef short  s16x8  __attribute__((ext_vector_type(8)));
typedef short  s16x4  __attribute__((ext_vector_type(4)));

__device__ __forceinline__ short f2bf(float f) {
  unsigned u = __float_as_uint(f);
  u += 0x7fffu + ((u >> 16) & 1u);   // RNE
  return (short)(u >> 16);
}

// ---------------------------------------------------------------------------
// K1: fused attention-score (bf16 MFMA) + segment pooling (p0,p1,p2, e*x, z, counts)
// One pass over x. Blocks own CONTIGUOUS 16-node tile ranges so each block
// spans ~3 segments -> few atomic flushes.
// ---------------------------------------------------------------------------
__global__ __launch_bounds__(256) void k_score_pool(
    const float* __restrict__ x, const int* __restrict__ batch, const int* __restrict__ mask,
    const float* __restrict__ aw1, const float* __restrict__ ab1,
    const float* __restrict__ aw2, const float* __restrict__ ab2,
    float* __restrict__ P, float* __restrict__ EX, float* __restrict__ Z, float* __restrict__ C,
    int nnodes) {
  __shared__ __align__(16) short xs[16][264];   // bf16 tile, padded stride (264*2=528B, 16B aligned)
  __shared__ __align__(16) float xsf[16][256];  // fp32 tile for exact pooling
  __shared__ float sred[4][16];
  __shared__ float e_lds[16];
  __shared__ int   seg_lds[16];
  __shared__ int   t_lds[16];

  const int tid  = threadIdx.x;
  const int lane = tid & 63;
  const int w    = tid >> 6;    // wave 0..3 -> cols [32w, 32w+32)
  const int quad = lane >> 4;
  const int l15  = lane & 15;

  // --- preload B fragments (aw1 cols for this wave) into registers, once per block ---
  // B-frag layout (16x16x32): elem j = B[k = kt*32 + quad*8 + j][n = l15]
  s16x8 bfrag[8][2];
  float ab1v[2], aw2v[2];
#pragma unroll
  for (int ct = 0; ct < 2; ++ct) {
    const int col = w * 32 + ct * 16 + l15;
    ab1v[ct] = ab1[col];
    aw2v[ct] = aw2[col];
#pragma unroll
    for (int kt = 0; kt < 8; ++kt) {
      s16x8 f;
#pragma unroll
      for (int j = 0; j < 8; ++j) {
        const int k = kt * 32 + quad * 8 + j;
        f[j] = f2bf(aw1[k * 128 + col]);
      }
      bfrag[kt][ct] = f;
    }
  }
  const float ab2v = ab2[0];

  const int ntiles = nnodes >> 4;
  const int tpb    = (ntiles + (int)gridDim.x - 1) / (int)gridDim.x;
  const int t_beg  = blockIdx.x * tpb;
  const int t_end  = min(t_beg + tpb, ntiles);

  // per-thread pooling accumulators for current segment (thread owns dim d = tid)
  float a0 = 0.f, a1 = 0.f, a2 = 0.f, aex = 0.f;
  float zacc = 0.f, cc0 = 0.f, cc1 = 0.f, cc2 = 0.f;
  int cur = -1;

  const int node_r = tid >> 4;          // staging: node within tile
  const int col0   = (tid & 15) * 16;   // staging: 16 consecutive cols

  for (int tile = t_beg; tile < t_end; ++tile) {
    const int node0 = tile * 16;
    // --- stage x tile: fp32 copy + bf16 copy ---
    const float* src = x + (size_t)(node0 + node_r) * 256 + col0;
#pragma unroll
    for (int c = 0; c < 4; ++c) {
      float4 v = reinterpret_cast<const float4*>(src)[c];
      reinterpret_cast<float4*>(&xsf[node_r][col0])[c] = v;
      s16x4 b; b[0] = f2bf(v.x); b[1] = f2bf(v.y); b[2] = f2bf(v.z); b[3] = f2bf(v.w);
      *reinterpret_cast<s16x4*>(&xs[node_r][col0 + c * 4]) = b;
    }
    if (tid < 16) {
      const int i = node0 + tid;
      seg_lds[tid] = batch[i];
      t_lds[tid]   = mask[i * 3 + 1] + 2 * mask[i * 3 + 2];
    }
    __syncthreads();

    // --- MFMA: h_pre(16x32 per wave) = x_tile @ aw1[:, wave cols] ---
    // A-frag: elem j = A[m = l15][k = kt*32 + quad*8 + j]
    s16x8 af[8];
#pragma unroll
    for (int kt = 0; kt < 8; ++kt)
      af[kt] = *reinterpret_cast<const s16x8*>(&xs[l15][kt * 32 + quad * 8]);

    float part[4] = {0.f, 0.f, 0.f, 0.f};
#pragma unroll
    for (int ct = 0; ct < 2; ++ct) {
      f32x4 acc = {0.f, 0.f, 0.f, 0.f};
#pragma unroll
      for (int kt = 0; kt < 8; ++kt)
        acc = __builtin_amdgcn_mfma_f32_16x16x32_bf16(af[kt], bfrag[kt][ct], acc, 0, 0, 0);
      // C/D layout: col = l15, row(node) = quad*4 + r
#pragma unroll
      for (int r = 0; r < 4; ++r)
        part[r] += tanhf(acc[r] + ab1v[ct]) * aw2v[ct];
    }
    // reduce over the 16 cols held across l15 lanes
#pragma unroll
    for (int off = 1; off < 16; off <<= 1) {
#pragma unroll
      for (int r = 0; r < 4; ++r) part[r] += __shfl_xor(part[r], off);
    }
    if (l15 == 0) {
#pragma unroll
      for (int r = 0; r < 4; ++r) sred[w][quad * 4 + r] = part[r];
    }
    __syncthreads();
    if (tid < 16) {
      const float s = ab2v + sred[0][tid] + sred[1][tid] + sred[2][tid] + sred[3][tid];
      e_lds[tid] = expf(s);
    }
    __syncthreads();

    // --- pooling: thread d accumulates p_type[d], e*x[d] for current segment ---
#pragma unroll 4
    for (int n = 0; n < 16; ++n) {
      const int seg = seg_lds[n];   // block-uniform
      if (seg != cur) {
        if (cur >= 0) {
          atomicAdd(&P[cur * 768 + tid], a0);
          atomicAdd(&P[cur * 768 + 256 + tid], a1);
          atomicAdd(&P[cur * 768 + 512 + tid], a2);
          atomicAdd(&EX[cur * 256 + tid], aex);
          if (tid == 0) {
            atomicAdd(&Z[cur], zacc);
            atomicAdd(&C[cur * 4 + 0], cc0);
            atomicAdd(&C[cur * 4 + 1], cc1);
            atomicAdd(&C[cur * 4 + 2], cc2);
          }
          a0 = a1 = a2 = aex = 0.f; zacc = 0.f; cc0 = cc1 = cc2 = 0.f;
        }
        cur = seg;
      }
      const float e  = e_lds[n];
      const float xv = xsf[n][tid];
      const int   t  = t_lds[n];    // block-uniform -> no divergence
      aex += e * xv;
      if (t == 0) a0 += xv; else if (t == 1) a1 += xv; else a2 += xv;
      if (tid == 0) {
        zacc += e;
        if (t == 0) cc0 += 1.f; else if (t == 1) cc1 += 1.f; else cc2 += 1.f;
      }
    }
    __syncthreads();  // protect xsf/xs/lds from next tile's staging
  }

  if (cur >= 0) {
    atomicAdd(&P[cur * 768 + tid], a0);
    atomicAdd(&P[cur * 768 + 256 + tid], a1);
    atomicAdd(&P[cur * 768 + 512 + tid], a2);
    atomicAdd(&EX[cur * 256 + tid], aex);
    if (tid == 0) {
      atomicAdd(&Z[cur], zacc);
      atomicAdd(&C[cur * 4 + 0], cc0);
      atomicAdd(&C[cur * 4 + 1], cc1);
      atomicAdd(&C[cur * 4 + 2], cc2);
    }
  }
}

// ---------------------------------------------------------------------------
// K2: finalize mean/attn pools into combined[:, 0:512]
// ---------------------------------------------------------------------------
__global__ __launch_bounds__(256) void k_finalize(
    const float* __restrict__ P, const float* __restrict__ EX,
    const float* __restrict__ Z, const float* __restrict__ C,
    float* __restrict__ comb) {
  const int b = blockIdx.x, d = threadIdx.x;
  const float p0 = P[b * 768 + d], p1 = P[b * 768 + 256 + d], p2 = P[b * 768 + 512 + d];
  const float cnt = C[b * 4 + 0] + C[b * 4 + 1] + C[b * 4 + 2];
  comb[(size_t)b * 768 + d]       = (p0 + p1 + p2) / cnt;
  comb[(size_t)b * 768 + 256 + d] = EX[b * 256 + d] / Z[b];
}

// ---------------------------------------------------------------------------
// K3a: phys_pool = [p0 p1 p2] @ [we;wv;wp] + c0*be + c1*bv + c2*bp -> comb[:,512:768]
// MT=8 rows, NT=128 cols per block.
// ---------------------------------------------------------------------------
__global__ __launch_bounds__(256) void k_phys(
    const float* __restrict__ P, const float* __restrict__ we, const float* __restrict__ wv,
    const float* __restrict__ wp, const float* __restrict__ be, const float* __restrict__ bv,
    const float* __restrict__ bp, const float* __restrict__ C, float* __restrict__ comb) {
  __shared__ __align__(16) float alds[768 * 8];
  const int tid = threadIdx.x;
  const int m0  = blockIdx.x * 8;
  {
    const int m = tid >> 5;
    const float* src = P + (size_t)(m0 + m) * 768;
    for (int k = (tid & 31); k < 768; k += 32) alds[k * 8 + m] = src[k];
  }
  __syncthreads();
  const int n  = blockIdx.y * 128 + (tid & 127);
  const int mg = tid >> 7;
  float acc[4] = {0.f, 0.f, 0.f, 0.f};
  const float* Ws[3] = {we, wv, wp};
  for (int part = 0; part < 3; ++part) {
    const float* __restrict__ W = Ws[part];
    const int koff = part * 256;
#pragma unroll 4
    for (int k = 0; k < 256; ++k) {
      const float wk = W[k * 256 + n];
      f32x4 a = *reinterpret_cast<const f32x4*>(&alds[(koff + k) * 8 + mg * 4]);
      acc[0] += a[0] * wk; acc[1] += a[1] * wk; acc[2] += a[2] * wk; acc[3] += a[3] * wk;
    }
  }
  const float ben = be[n], bvn = bv[n], bpn = bp[n];
#pragma unroll
  for (int mi = 0; mi < 4; ++mi) {
    const int row = m0 + mg * 4 + mi;
    const float v = acc[mi] + C[row * 4 + 0] * ben + C[row * 4 + 1] * bvn + C[row * 4 + 2] * bpn;
    comb[(size_t)row * 768 + 512 + n] = v;
  }
}

// ---------------------------------------------------------------------------
// K3b: h = silu(comb @ w1 + b1)   (1024x768)@(768x512)
// ---------------------------------------------------------------------------
__global__ __launch_bounds__(256) void k_mlp1(
    const float* __restrict__ A, const float* __restrict__ W, const float* __restrict__ bias,
    float* __restrict__ H) {
  __shared__ __align__(16) float alds[768 * 8];
  const int tid = threadIdx.x;
  const int m0  = blockIdx.x * 8;
  {
    const int m = tid >> 5;
    const float* src = A + (size_t)(m0 + m) * 768;
    for (int k = (tid & 31); k < 768; k += 32) alds[k * 8 + m] = src[k];
  }
  __syncthreads();
  const int n  = blockIdx.y * 128 + (tid & 127);
  const int mg = tid >> 7;
  float acc[4] = {0.f, 0.f, 0.f, 0.f};
#pragma unroll 4
  for (int k = 0; k < 768; ++k) {
    const float wk = W[k * 512 + n];
    f32x4 a = *reinterpret_cast<const f32x4*>(&alds[k * 8 + mg * 4]);
    acc[0] += a[0] * wk; acc[1] += a[1] * wk; acc[2] += a[2] * wk; acc[3] += a[3] * wk;
  }
  const float bn = bias[n];
#pragma unroll
  for (int mi = 0; mi < 4; ++mi) {
    const int row = m0 + mg * 4 + mi;
    const float v = acc[mi] + bn;
    H[(size_t)row * 512 + n] = v / (1.f + expf(-v));   // silu
  }
}

// ---------------------------------------------------------------------------
// K3c: out = h @ w2 + b2   (1024x512)@(512x256)
// ---------------------------------------------------------------------------
__global__ __launch_bounds__(256) void k_mlp2(
    const float* __restrict__ A, const float* __restrict__ W, const float* __restrict__ bias,
    float* __restrict__ out) {
  __shared__ __align__(16) float alds[512 * 8];
  const int tid = threadIdx.x;
  const int m0  = blockIdx.x * 8;
  {
    const int m = tid >> 5;
    const float* src = A + (size_t)(m0 + m) * 512;
    for (int k = (tid & 31); k < 512; k += 32) alds[k * 8 + m] = src[k];
  }
  __syncthreads();
  const int n  = blockIdx.y * 128 + (tid & 127);
  const int mg = tid >> 7;
  float acc[4] = {0.f, 0.f, 0.f, 0.f};
#pragma unroll 4
  for (int k = 0; k < 512; ++k) {
    const float wk = W[k * 256 + n];
    f32x4 a = *reinterpret_cast<const f32x4*>(&alds[k * 8 + mg * 4]);
    acc[0] += a[0] * wk; acc[1] += a[1] * wk; acc[2] += a[2] * wk; acc[3] += a[3] * wk;
  }
  const float bn = bias[n];
#pragma unroll
  for (int mi = 0; mi < 4; ++mi) {
    const int row = m0 + mg * 4 + mi;
    out[(size_t)row * 256 + n] = acc[mi] + bn;
  }
}

// ---------------------------------------------------------------------------
extern "C" void kernel_launch(void* const* d_in, const int* in_sizes, int n_in,
                              void* d_out, int out_size, void* d_ws, size_t ws_size,
                              hipStream_t stream) {
  const float* x    = (const float*)d_in[0];
  const int*   batch= (const int*)  d_in[1];
  const int*   mask = (const int*)  d_in[2];
  // d_in[3] = num_segments (==1024, hardcoded)
  const float* aw1  = (const float*)d_in[4];
  const float* ab1  = (const float*)d_in[5];
  const float* aw2  = (const float*)d_in[6];
  const float* ab2  = (const float*)d_in[7];
  const float* we   = (const float*)d_in[8];
  const float* be   = (const float*)d_in[9];
  const float* wv   = (const float*)d_in[10];
  const float* bv   = (const float*)d_in[11];
  const float* wp   = (const float*)d_in[12];
  const float* bp   = (const float*)d_in[13];
  const float* w1   = (const float*)d_in[14];
  const float* b1   = (const float*)d_in[15];
  const float* w2   = (const float*)d_in[16];
  const float* b2   = (const float*)d_in[17];
  float* out = (float*)d_out;
  const int nn = in_sizes[1];   // 200000 nodes

  float* ws   = (float*)d_ws;
  float* P    = ws;                       // 1024*768
  float* EXs  = P    + 1024 * 768;        // 1024*256
  float* Zs   = EXs  + 1024 * 256;        // 1024
  float* Cs   = Zs   + 1024;              // 1024*4
  float* comb = Cs   + 1024 * 4;          // 1024*768
  float* hbuf = comb + 1024 * 768;        // 1024*512

  const size_t zbytes = (size_t)(1024 * 768 + 1024 * 256 + 1024 + 1024 * 4) * sizeof(float);
  hipMemsetAsync(P, 0, zbytes, stream);

  k_score_pool<<<1024, 256, 0, stream>>>(x, batch, mask, aw1, ab1, aw2, ab2, P, EXs, Zs, Cs, nn);
  k_finalize  <<<1024, 256, 0, stream>>>(P, EXs, Zs, Cs, comb);
  k_phys      <<<dim3(128, 2), 256, 0, stream>>>(P, we, wv, wp, be, bv, bp, Cs, comb);
  k_mlp1      <<<dim3(128, 4), 256, 0, stream>>>(comb, w1, b1, hbuf);
  k_mlp2      <<<dim3(128, 2), 256, 0, stream>>>(hbuf, w2, b2, out);
}

// Round 3
// 481.336 us; speedup vs baseline: 1.3625x; 1.3625x over previous
//
#include <hip/hip_runtime.h>

typedef float  f32x4  __attribute__((ext_vector_type(4)));
typedef short  s16x8  __attribute__((ext_vector_type(8)));
typedef short  s16x4  __attribute__((ext_vector_type(4)));

typedef const __attribute__((address_space(1))) unsigned int* gptr_t;
typedef __attribute__((address_space(3))) unsigned int*       lptr_t;

__device__ __forceinline__ short f2bf(float f) {
  unsigned u = __float_as_uint(f);
  u += 0x7fffu + ((u >> 16) & 1u);   // RNE
  return (short)(u >> 16);
}

__device__ __forceinline__ float tanh_fast(float x) {
  // tanh(x) = 1 - 2/(exp(2x)+1); exact limits at +/-inf, ~1e-7 rel err.
  const float e = __expf(2.0f * x);
  return 1.0f - 2.0f / (e + 1.0f);
}

// ---------------------------------------------------------------------------
// K1: fused attention-score (bf16 MFMA) + segment pooling.
// - global_load_lds (width 16) DMA staging, double-buffered fp32 tile
// - bank-conflict-free LDS layouts (row stride 264)
// - 3 barriers/tile; DMA for t+1 issued after B2 (only loop-top barrier drains it)
// ---------------------------------------------------------------------------
__global__ __launch_bounds__(256) void k_score_pool(
    const float* __restrict__ x, const int* __restrict__ batch, const int* __restrict__ mask,
    const float* __restrict__ aw1, const float* __restrict__ ab1,
    const float* __restrict__ aw2, const float* __restrict__ ab2,
    float* __restrict__ P, float* __restrict__ EX, float* __restrict__ Z, float* __restrict__ C,
    int nnodes) {
  __shared__ __align__(16) float xsf[2][16][264];  // fp32 x tile, dbuf; stride 264 (16B aligned, skew 8 banks/row)
  __shared__ __align__(16) short xs[16][264];      // bf16 x tile (single buffer: see barrier proofs)
  __shared__ __align__(16) float sred[4][16];
  __shared__ __align__(16) float e_sh[4][16];
  __shared__ int   seg_lds[16];
  __shared__ int   t_lds[16];

  const int tid  = threadIdx.x;
  const int lane = tid & 63;
  const int w    = tid >> 6;    // wave 0..3 -> score cols [32w, 32w+32)
  const int quad = lane >> 4;
  const int l15  = lane & 15;

  // --- preload B fragments (aw1 cols for this wave), once per block ---
  // B-frag (16x16x32): elem j = B[k = kt*32 + quad*8 + j][n = l15]
  s16x8 bfrag[8][2];
  float ab1v[2], aw2v[2];
#pragma unroll
  for (int ct = 0; ct < 2; ++ct) {
    const int col = w * 32 + ct * 16 + l15;
    ab1v[ct] = ab1[col];
    aw2v[ct] = aw2[col];
#pragma unroll
    for (int kt = 0; kt < 8; ++kt) {
      s16x8 f;
#pragma unroll
      for (int j = 0; j < 8; ++j) {
        const int k = kt * 32 + quad * 8 + j;
        f[j] = f2bf(aw1[k * 128 + col]);
      }
      bfrag[kt][ct] = f;
    }
  }
  const float ab2v = ab2[0];

  const int ntiles = nnodes >> 4;
  const int tpb    = (ntiles + (int)gridDim.x - 1) / (int)gridDim.x;
  const int t_beg  = blockIdx.x * tpb;
  const int t_end  = min(t_beg + tpb, ntiles);
  if (t_beg >= t_end) return;   // whole block exits: no barrier mismatch

  // DMA stage: wave w stages rows 4w..4w+3; one 1KB instruction per row
  auto stage = [&](int tile, int buf) {
    const float* base = x + (size_t)tile * (16 * 256);
#pragma unroll
    for (int j = 0; j < 4; ++j) {
      const int r = 4 * w + j;
      const float* g = base + r * 256 + lane * 4;  // lane*16B, contiguous row
      __builtin_amdgcn_global_load_lds((gptr_t)g, (lptr_t)(&xsf[buf][r][0]), 16, 0, 0);
    }
  };

  stage(t_beg, 0);

  float a0 = 0.f, a1 = 0.f, a2 = 0.f, aex = 0.f;
  float zacc = 0.f, cc0 = 0.f, cc1 = 0.f, cc2 = 0.f;
  int cur = -1;

  const int rc   = tid >> 4;    // cvt: row
  const int ct16 = tid & 15;    // cvt: col lane

  for (int tile = t_beg; tile < t_end; ++tile) {
    const int buf   = (tile - t_beg) & 1;
    const int node0 = tile * 16;

    __syncthreads();  // TOP: drains DMA for this tile (vmcnt0 before s_barrier);
                      // fences pool-reads(buf, t-2) < here < DMA-writes(buf, t)

    if (tid < 16) {
      const int i = node0 + tid;
      seg_lds[tid] = batch[i];
      t_lds[tid]   = mask[i * 3 + 1] + 2 * mask[i * 3 + 2];
    }
    // cvt fp32 -> bf16 tile. Cols 4*ct16 + 64c: reads 2-way (free), writes b64 optimal.
#pragma unroll
    for (int c = 0; c < 4; ++c) {
      const int col = 4 * ct16 + 64 * c;
      f32x4 v = *reinterpret_cast<const f32x4*>(&xsf[buf][rc][col]);
      s16x4 b; b[0] = f2bf(v[0]); b[1] = f2bf(v[1]); b[2] = f2bf(v[2]); b[3] = f2bf(v[3]);
      *reinterpret_cast<s16x4*>(&xs[rc][col]) = b;
    }
    __syncthreads();  // B1: xs + seg_lds ready
    // xs single-buffer proof: reads(t) < B2(t) < TOP(t+1) < writes(t+1).

    // --- MFMA: scores for 16 nodes x this wave's 32 cols ---
    s16x8 af[8];
#pragma unroll
    for (int kt = 0; kt < 8; ++kt)
      af[kt] = *reinterpret_cast<const s16x8*>(&xs[l15][kt * 32 + quad * 8]);

    float part[4] = {0.f, 0.f, 0.f, 0.f};
#pragma unroll
    for (int ct = 0; ct < 2; ++ct) {
      f32x4 acc = {0.f, 0.f, 0.f, 0.f};
#pragma unroll
      for (int kt = 0; kt < 8; ++kt)
        acc = __builtin_amdgcn_mfma_f32_16x16x32_bf16(af[kt], bfrag[kt][ct], acc, 0, 0, 0);
#pragma unroll
      for (int r = 0; r < 4; ++r)
        part[r] += tanh_fast(acc[r] + ab1v[ct]) * aw2v[ct];
    }
#pragma unroll
    for (int off = 1; off < 16; off <<= 1) {
#pragma unroll
      for (int r = 0; r < 4; ++r) part[r] += __shfl_xor(part[r], off);
    }
    if (l15 == 0) {
#pragma unroll
      for (int r = 0; r < 4; ++r) sred[w][quad * 4 + r] = part[r];
    }
    __syncthreads();  // B2: sred ready

    if (tile + 1 < t_end) stage(tile + 1, buf ^ 1);  // prefetch overlaps e+pooling

    // wave-private exp broadcast (in-wave LDS ordering; no barrier needed)
    if (lane < 16) {
      const float s = ab2v + sred[0][lane] + sred[1][lane] + sred[2][lane] + sred[3][lane];
      e_sh[w][lane] = __expf(s);
    }
    float er[16];
#pragma unroll
    for (int j = 0; j < 4; ++j) {
      f32x4 ev = *reinterpret_cast<const f32x4*>(&e_sh[w][4 * j]);
      er[4 * j] = ev[0]; er[4 * j + 1] = ev[1]; er[4 * j + 2] = ev[2]; er[4 * j + 3] = ev[3];
    }

    // --- pooling: thread d=tid accumulates over the 16 nodes ---
#pragma unroll
    for (int n = 0; n < 16; ++n) {
      const int seg = seg_lds[n];   // block-uniform
      if (seg != cur) {
        if (cur >= 0) {
          atomicAdd(&P[cur * 768 + tid], a0);
          atomicAdd(&P[cur * 768 + 256 + tid], a1);
          atomicAdd(&P[cur * 768 + 512 + tid], a2);
          atomicAdd(&EX[cur * 256 + tid], aex);
          if (tid == 0) {
            atomicAdd(&Z[cur], zacc);
            atomicAdd(&C[cur * 4 + 0], cc0);
            atomicAdd(&C[cur * 4 + 1], cc1);
            atomicAdd(&C[cur * 4 + 2], cc2);
          }
          a0 = a1 = a2 = aex = 0.f; zacc = 0.f; cc0 = cc1 = cc2 = 0.f;
        }
        cur = seg;
      }
      const float e  = er[n];
      const float xv = xsf[buf][n][tid];   // bank (8n+tid)%32: conflict-free
      const int   t  = t_lds[n];           // block-uniform
      aex += e * xv;
      if (t == 0) a0 += xv; else if (t == 1) a1 += xv; else a2 += xv;
      if (tid == 0) {
        zacc += e;
        if (t == 0) cc0 += 1.f; else if (t == 1) cc1 += 1.f; else cc2 += 1.f;
      }
    }
  }

  if (cur >= 0) {
    atomicAdd(&P[cur * 768 + tid], a0);
    atomicAdd(&P[cur * 768 + 256 + tid], a1);
    atomicAdd(&P[cur * 768 + 512 + tid], a2);
    atomicAdd(&EX[cur * 256 + tid], aex);
    if (tid == 0) {
      atomicAdd(&Z[cur], zacc);
      atomicAdd(&C[cur * 4 + 0], cc0);
      atomicAdd(&C[cur * 4 + 1], cc1);
      atomicAdd(&C[cur * 4 + 2], cc2);
    }
  }
}

// ---------------------------------------------------------------------------
// K2: finalize mean/attn pools into combined[:, 0:512]
// ---------------------------------------------------------------------------
__global__ __launch_bounds__(256) void k_finalize(
    const float* __restrict__ P, const float* __restrict__ EX,
    const float* __restrict__ Z, const float* __restrict__ C,
    float* __restrict__ comb) {
  const int b = blockIdx.x, d = threadIdx.x;
  const float p0 = P[b * 768 + d], p1 = P[b * 768 + 256 + d], p2 = P[b * 768 + 512 + d];
  const float cnt = C[b * 4 + 0] + C[b * 4 + 1] + C[b * 4 + 2];
  comb[(size_t)b * 768 + d]       = (p0 + p1 + p2) / cnt;
  comb[(size_t)b * 768 + 256 + d] = EX[b * 256 + d] / Z[b];
}

// ---------------------------------------------------------------------------
// K3a: phys_pool = [p0 p1 p2] @ [we;wv;wp] + counts-weighted biases
// ---------------------------------------------------------------------------
__global__ __launch_bounds__(256) void k_phys(
    const float* __restrict__ P, const float* __restrict__ we, const float* __restrict__ wv,
    const float* __restrict__ wp, const float* __restrict__ be, const float* __restrict__ bv,
    const float* __restrict__ bp, const float* __restrict__ C, float* __restrict__ comb) {
  __shared__ __align__(16) float alds[768 * 8];
  const int tid = threadIdx.x;
  const int m0  = blockIdx.x * 8;
  {
    const int m = tid >> 5;
    const float* src = P + (size_t)(m0 + m) * 768;
    for (int k = (tid & 31); k < 768; k += 32) alds[k * 8 + m] = src[k];
  }
  __syncthreads();
  const int n  = blockIdx.y * 128 + (tid & 127);
  const int mg = tid >> 7;
  float acc[4] = {0.f, 0.f, 0.f, 0.f};
  const float* Ws[3] = {we, wv, wp};
  for (int part = 0; part < 3; ++part) {
    const float* __restrict__ W = Ws[part];
    const int koff = part * 256;
#pragma unroll 16
    for (int k = 0; k < 256; ++k) {
      const float wk = W[k * 256 + n];
      f32x4 a = *reinterpret_cast<const f32x4*>(&alds[(koff + k) * 8 + mg * 4]);
      acc[0] += a[0] * wk; acc[1] += a[1] * wk; acc[2] += a[2] * wk; acc[3] += a[3] * wk;
    }
  }
  const float ben = be[n], bvn = bv[n], bpn = bp[n];
#pragma unroll
  for (int mi = 0; mi < 4; ++mi) {
    const int row = m0 + mg * 4 + mi;
    const float v = acc[mi] + C[row * 4 + 0] * ben + C[row * 4 + 1] * bvn + C[row * 4 + 2] * bpn;
    comb[(size_t)row * 768 + 512 + n] = v;
  }
}

// ---------------------------------------------------------------------------
// K3b: h = silu(comb @ w1 + b1)   (1024x768)@(768x512)
// ---------------------------------------------------------------------------
__global__ __launch_bounds__(256) void k_mlp1(
    const float* __restrict__ A, const float* __restrict__ W, const float* __restrict__ bias,
    float* __restrict__ H) {
  __shared__ __align__(16) float alds[768 * 8];
  const int tid = threadIdx.x;
  const int m0  = blockIdx.x * 8;
  {
    const int m = tid >> 5;
    const float* src = A + (size_t)(m0 + m) * 768;
    for (int k = (tid & 31); k < 768; k += 32) alds[k * 8 + m] = src[k];
  }
  __syncthreads();
  const int n  = blockIdx.y * 128 + (tid & 127);
  const int mg = tid >> 7;
  float acc[4] = {0.f, 0.f, 0.f, 0.f};
#pragma unroll 16
  for (int k = 0; k < 768; ++k) {
    const float wk = W[k * 512 + n];
    f32x4 a = *reinterpret_cast<const f32x4*>(&alds[k * 8 + mg * 4]);
    acc[0] += a[0] * wk; acc[1] += a[1] * wk; acc[2] += a[2] * wk; acc[3] += a[3] * wk;
  }
  const float bn = bias[n];
#pragma unroll
  for (int mi = 0; mi < 4; ++mi) {
    const int row = m0 + mg * 4 + mi;
    const float v = acc[mi] + bn;
    H[(size_t)row * 512 + n] = v / (1.f + __expf(-v));   // silu
  }
}

// ---------------------------------------------------------------------------
// K3c: out = h @ w2 + b2   (1024x512)@(512x256)
// ---------------------------------------------------------------------------
__global__ __launch_bounds__(256) void k_mlp2(
    const float* __restrict__ A, const float* __restrict__ W, const float* __restrict__ bias,
    float* __restrict__ out) {
  __shared__ __align__(16) float alds[512 * 8];
  const int tid = threadIdx.x;
  const int m0  = blockIdx.x * 8;
  {
    const int m = tid >> 5;
    const float* src = A + (size_t)(m0 + m) * 512;
    for (int k = (tid & 31); k < 512; k += 32) alds[k * 8 + m] = src[k];
  }
  __syncthreads();
  const int n  = blockIdx.y * 128 + (tid & 127);
  const int mg = tid >> 7;
  float acc[4] = {0.f, 0.f, 0.f, 0.f};
#pragma unroll 16
  for (int k = 0; k < 512; ++k) {
    const float wk = W[k * 256 + n];
    f32x4 a = *reinterpret_cast<const f32x4*>(&alds[k * 8 + mg * 4]);
    acc[0] += a[0] * wk; acc[1] += a[1] * wk; acc[2] += a[2] * wk; acc[3] += a[3] * wk;
  }
  const float bn = bias[n];
#pragma unroll
  for (int mi = 0; mi < 4; ++mi) {
    const int row = m0 + mg * 4 + mi;
    out[(size_t)row * 256 + n] = acc[mi] + bn;
  }
}

// ---------------------------------------------------------------------------
extern "C" void kernel_launch(void* const* d_in, const int* in_sizes, int n_in,
                              void* d_out, int out_size, void* d_ws, size_t ws_size,
                              hipStream_t stream) {
  const float* x    = (const float*)d_in[0];
  const int*   batch= (const int*)  d_in[1];
  const int*   mask = (const int*)  d_in[2];
  const float* aw1  = (const float*)d_in[4];
  const float* ab1  = (const float*)d_in[5];
  const float* aw2  = (const float*)d_in[6];
  const float* ab2  = (const float*)d_in[7];
  const float* we   = (const float*)d_in[8];
  const float* be   = (const float*)d_in[9];
  const float* wv   = (const float*)d_in[10];
  const float* bv   = (const float*)d_in[11];
  const float* wp   = (const float*)d_in[12];
  const float* bp   = (const float*)d_in[13];
  const float* w1   = (const float*)d_in[14];
  const float* b1   = (const float*)d_in[15];
  const float* w2   = (const float*)d_in[16];
  const float* b2   = (const float*)d_in[17];
  float* out = (float*)d_out;
  const int nn = in_sizes[1];   // 200000 nodes

  float* ws   = (float*)d_ws;
  float* P    = ws;                       // 1024*768
  float* EXs  = P    + 1024 * 768;        // 1024*256
  float* Zs   = EXs  + 1024 * 256;        // 1024
  float* Cs   = Zs   + 1024;              // 1024*4
  float* comb = Cs   + 1024 * 4;          // 1024*768
  float* hbuf = comb + 1024 * 768;        // 1024*512

  const size_t zbytes = (size_t)(1024 * 768 + 1024 * 256 + 1024 + 1024 * 4) * sizeof(float);
  hipMemsetAsync(P, 0, zbytes, stream);

  k_score_pool<<<1024, 256, 0, stream>>>(x, batch, mask, aw1, ab1, aw2, ab2, P, EXs, Zs, Cs, nn);
  k_finalize  <<<1024, 256, 0, stream>>>(P, EXs, Zs, Cs, comb);
  k_phys      <<<dim3(128, 2), 256, 0, stream>>>(P, we, wv, wp, be, bv, bp, Cs, comb);
  k_mlp1      <<<dim3(128, 4), 256, 0, stream>>>(comb, w1, b1, hbuf);
  k_mlp2      <<<dim3(128, 2), 256, 0, stream>>>(hbuf, w2, b2, out);
}

// Round 4
// 373.165 us; speedup vs baseline: 1.7574x; 1.2899x over previous
//
#include <hip/hip_runtime.h>

typedef float  f32x4  __attribute__((ext_vector_type(4)));
typedef short  s16x8  __attribute__((ext_vector_type(8)));
typedef short  s16x4  __attribute__((ext_vector_type(4)));

__device__ __forceinline__ short f2bf(float f) {
  unsigned u = __float_as_uint(f);
  u += 0x7fffu + ((u >> 16) & 1u);   // RNE
  return (short)(u >> 16);
}
__device__ __forceinline__ float bf2f(unsigned short us) {
  return __uint_as_float(((unsigned)us) << 16);
}
__device__ __forceinline__ float tanh_fast(float x) {
  const float e = __expf(2.0f * x);
  return 1.0f - 2.0f / (e + 1.0f);
}

// ---------------------------------------------------------------------------
// K0: convert+transpose weights to bf16 once.
//  Awt[128][256]  <- aw1(256x128)      blocks [0,128)
//  Wpt[256][768]  <- [we;wv;wp]^T      blocks [128,896)
//  W1t[512][768]  <- w1^T              blocks [896,2432)
//  W2t[256][512]  <- w2^T              blocks [2432,2944)
// ---------------------------------------------------------------------------
__global__ __launch_bounds__(256) void k_cvtw(
    const float* __restrict__ aw1, const float* __restrict__ we, const float* __restrict__ wv,
    const float* __restrict__ wp, const float* __restrict__ w1, const float* __restrict__ w2,
    unsigned short* __restrict__ Awt, unsigned short* __restrict__ Wpt,
    unsigned short* __restrict__ W1t, unsigned short* __restrict__ W2t) {
  const int b = blockIdx.x, tid = threadIdx.x;
  if (b < 128) {
    const int e = b * 256 + tid, n = e >> 8, k = e & 255;
    Awt[e] = (unsigned short)f2bf(aw1[k * 128 + n]);
  } else if (b < 896) {
    const int e = (b - 128) * 256 + tid, n = e / 768, k = e % 768;
    const int part = k >> 8, kk = k & 255;
    const float* W = (part == 0) ? we : ((part == 1) ? wv : wp);
    Wpt[e] = (unsigned short)f2bf(W[kk * 256 + n]);
  } else if (b < 2432) {
    const int e = (b - 896) * 256 + tid, n = e / 768, k = e % 768;
    W1t[e] = (unsigned short)f2bf(w1[k * 512 + n]);
  } else {
    const int e = (b - 2432) * 256 + tid, n = e >> 9, k = e & 511;
    W2t[e] = (unsigned short)f2bf(w2[k * 256 + n]);
  }
}

// ---------------------------------------------------------------------------
// K1: fused attention-score (bf16 MFMA) + segment pooling.
// 32-node tiles, register staging (deep MLP), bf16-only dbuf LDS,
// 2 barriers/tile, per-block seg/type preload.
// ---------------------------------------------------------------------------
__global__ __launch_bounds__(256) void k_score_pool(
    const float* __restrict__ x, const int* __restrict__ batch, const int* __restrict__ mask,
    const unsigned short* __restrict__ Awt, const float* __restrict__ ab1,
    const float* __restrict__ aw2, const float* __restrict__ ab2,
    float* __restrict__ P, float* __restrict__ EX, float* __restrict__ ZC,
    int nnodes) {
  __shared__ __align__(16) short xs[2][32][264];   // bf16 x, dbuf (33.8 KB)
  __shared__ __align__(16) float sred[4][32];
  __shared__ __align__(16) float e_sh[4][32];      // per-wave copies (no barrier needed)
  __shared__ int st_all[320];                      // seg*4+type for block's nodes

  const int tid  = threadIdx.x;
  const int lane = tid & 63;
  const int w    = tid >> 6;    // wave -> score cols [32w, 32w+32)
  const int quad = lane >> 4;
  const int l15  = lane & 15;

  // B-frags from pre-transposed bf16 aw1: frag j = aw1[k=kt*32+quad*8+j][col]
  s16x8 bfrag[8][2];
  float ab1v[2], aw2v[2];
#pragma unroll
  for (int ct = 0; ct < 2; ++ct) {
    const int col = w * 32 + ct * 16 + l15;
    ab1v[ct] = ab1[col];
    aw2v[ct] = aw2[col];
    const s16x8* bp = reinterpret_cast<const s16x8*>(Awt + (size_t)col * 256);
#pragma unroll
    for (int kt = 0; kt < 8; ++kt) bfrag[kt][ct] = bp[kt * 4 + quad];
  }
  const float ab2v = ab2[0];

  const int tiles = nnodes >> 5;                                // 6250
  const int tpb   = (tiles + (int)gridDim.x - 1) / (int)gridDim.x;
  const int t_beg = blockIdx.x * tpb;
  const int t_end = min(t_beg + tpb, tiles);
  if (t_beg >= t_end) return;   // whole-block exit: no barrier mismatch

  { // preload seg/type for the whole block range
    const int nodes0 = t_beg * 32, nblk = (t_end - t_beg) * 32;
    for (int i = tid; i < nblk; i += 256) {
      const int g = nodes0 + i;
      st_all[i] = batch[g] * 4 + mask[g * 3 + 1] + 2 * mask[g * 3 + 2];
    }
  }

  f32x4 stg[8];
  auto load_regs = [&](int tile) {
    const f32x4* xp = reinterpret_cast<const f32x4*>(x + (size_t)tile * 8192);
#pragma unroll
    for (int i = 0; i < 8; ++i) stg[i] = xp[tid + 256 * i];
  };
  const int col4 = (tid & 63) * 4;
  auto cvt_write = [&](int b) {
#pragma unroll
    for (int i = 0; i < 8; ++i) {
      const int row = (tid >> 6) + 4 * i;
      s16x4 v; v[0] = f2bf(stg[i][0]); v[1] = f2bf(stg[i][1]);
      v[2] = f2bf(stg[i][2]); v[3] = f2bf(stg[i][3]);
      *reinterpret_cast<s16x4*>(&xs[b][row][col4]) = v;
    }
  };

  load_regs(t_beg);
  cvt_write(0);
  __syncthreads();   // buf0 + st_all ready

  float a0 = 0.f, a1 = 0.f, a2 = 0.f, aex = 0.f, zc = 0.f;
  int cur = -1;

  auto flush = [&]() {
    atomicAdd(&P[cur * 768 + tid], a0);
    atomicAdd(&P[cur * 768 + 256 + tid], a1);
    atomicAdd(&P[cur * 768 + 512 + tid], a2);
    atomicAdd(&EX[cur * 256 + tid], aex);
    if (tid < 4) atomicAdd(&ZC[cur * 4 + tid], zc);
    a0 = a1 = a2 = aex = zc = 0.f;
  };

  for (int tile = t_beg; tile < t_end; ++tile) {
    const int buf = (tile - t_beg) & 1;
    const bool more = (tile + 1 < t_end);
    if (more) load_regs(tile + 1);   // issue loads early: in flight all iteration

    // --- MFMA scores: 32 nodes x this wave's 32 cols ---
#pragma unroll
    for (int ng = 0; ng < 2; ++ng) {
      s16x8 af[8];
#pragma unroll
      for (int kt = 0; kt < 8; ++kt)
        af[kt] = *reinterpret_cast<const s16x8*>(&xs[buf][16 * ng + l15][kt * 32 + quad * 8]);
      float part[4] = {0.f, 0.f, 0.f, 0.f};
#pragma unroll
      for (int ct = 0; ct < 2; ++ct) {
        f32x4 acc = {0.f, 0.f, 0.f, 0.f};
#pragma unroll
        for (int kt = 0; kt < 8; ++kt)
          acc = __builtin_amdgcn_mfma_f32_16x16x32_bf16(af[kt], bfrag[kt][ct], acc, 0, 0, 0);
#pragma unroll
        for (int r = 0; r < 4; ++r)
          part[r] += tanh_fast(acc[r] + ab1v[ct]) * aw2v[ct];
      }
#pragma unroll
      for (int off = 1; off < 16; off <<= 1) {
#pragma unroll
        for (int r = 0; r < 4; ++r) part[r] += __shfl_xor(part[r], off);
      }
      if (l15 == 0) {
#pragma unroll
        for (int r = 0; r < 4; ++r) sred[w][16 * ng + quad * 4 + r] = part[r];
      }
    }
    __syncthreads();   // A: sred ready

    if (lane < 32) {
      const float s = ab2v + sred[0][lane] + sred[1][lane] + sred[2][lane] + sred[3][lane];
      e_sh[w][lane] = __expf(s);   // per-wave copy; read after in-wave write: no barrier
    }

    // --- pooling: thread d=tid over the 32 nodes ---
    const int base = (tile - t_beg) * 32;
#pragma unroll
    for (int n = 0; n < 32; ++n) {
      const int st  = st_all[base + n];     // block-uniform
      const int seg = st >> 2, t = st & 3;
      if (seg != cur) { if (cur >= 0) flush(); cur = seg; }
      const float e  = e_sh[w][n];
      const float xv = bf2f((unsigned short)xs[buf][n][tid]);
      aex += e * xv;
      if (t == 0) a0 += xv; else if (t == 1) a1 += xv; else a2 += xv;
      if (tid < 4) zc += (tid == 0) ? e : ((t == tid - 1) ? 1.f : 0.f);
    }

    if (more) cvt_write(buf ^ 1);   // consume staged regs late (latency covered)
    __syncthreads();   // B: next buf ready; protects xs/sred intervals
  }
  if (cur >= 0) flush();
}

// ---------------------------------------------------------------------------
// K2: finalize mean/attn pools into combined[:, 0:512]
// ---------------------------------------------------------------------------
__global__ __launch_bounds__(256) void k_finalize(
    const float* __restrict__ P, const float* __restrict__ EX,
    const float* __restrict__ ZC, float* __restrict__ comb) {
  const int b = blockIdx.x, d = threadIdx.x;
  const float p0 = P[b * 768 + d], p1 = P[b * 768 + 256 + d], p2 = P[b * 768 + 512 + d];
  const float cnt = ZC[b * 4 + 1] + ZC[b * 4 + 2] + ZC[b * 4 + 3];
  comb[(size_t)b * 768 + d]       = (p0 + p1 + p2) / cnt;
  comb[(size_t)b * 768 + 256 + d] = EX[b * 256 + d] / ZC[b * 4];
}

// ---------------------------------------------------------------------------
// MFMA GEMM blocks: 16 rows x 64 cols, A-panel staged bf16 in LDS,
// B-frags preloaded up front from pre-transposed bf16 weights.
// ---------------------------------------------------------------------------
__global__ __launch_bounds__(256) void k_phys(
    const float* __restrict__ P, const unsigned short* __restrict__ Wpt,
    const float* __restrict__ be, const float* __restrict__ bv, const float* __restrict__ bp,
    const float* __restrict__ ZC, float* __restrict__ comb) {
  __shared__ __align__(16) short as16[16][776];
  const int tid = threadIdx.x, lane = tid & 63, w = tid >> 6;
  const int quad = lane >> 4, l15 = lane & 15;
  const int rowbase = blockIdx.x * 16;
  const int col = blockIdx.y * 64 + w * 16 + l15;

  s16x8 bfr[24];
  const s16x8* bpf = reinterpret_cast<const s16x8*>(Wpt + (size_t)col * 768);
#pragma unroll
  for (int kt = 0; kt < 24; ++kt) bfr[kt] = bpf[kt * 4 + quad];

  const f32x4* ap = reinterpret_cast<const f32x4*>(P + (size_t)rowbase * 768);
#pragma unroll
  for (int i = 0; i < 12; ++i) {
    const int ci = tid + 256 * i;
    f32x4 v = ap[ci];
    const int row = ci / 192, c4 = (ci % 192) * 4;
    s16x4 b; b[0] = f2bf(v[0]); b[1] = f2bf(v[1]); b[2] = f2bf(v[2]); b[3] = f2bf(v[3]);
    *reinterpret_cast<s16x4*>(&as16[row][c4]) = b;
  }
  __syncthreads();

  f32x4 acc = {0.f, 0.f, 0.f, 0.f};
#pragma unroll
  for (int kt = 0; kt < 24; ++kt) {
    s16x8 af = *reinterpret_cast<const s16x8*>(&as16[l15][kt * 32 + quad * 8]);
    acc = __builtin_amdgcn_mfma_f32_16x16x32_bf16(af, bfr[kt], acc, 0, 0, 0);
  }
  const float ben = be[col], bvn = bv[col], bpn = bp[col];
#pragma unroll
  for (int r = 0; r < 4; ++r) {
    const int row = rowbase + quad * 4 + r;
    const float v = acc[r] + ZC[row * 4 + 1] * ben + ZC[row * 4 + 2] * bvn + ZC[row * 4 + 3] * bpn;
    comb[(size_t)row * 768 + 512 + col] = v;
  }
}

__global__ __launch_bounds__(256) void k_mlp1(
    const float* __restrict__ A, const unsigned short* __restrict__ W1t,
    const float* __restrict__ b1, float* __restrict__ H) {
  __shared__ __align__(16) short as16[16][776];
  const int tid = threadIdx.x, lane = tid & 63, w = tid >> 6;
  const int quad = lane >> 4, l15 = lane & 15;
  const int rowbase = blockIdx.x * 16;
  const int col = blockIdx.y * 64 + w * 16 + l15;

  s16x8 bfr[24];
  const s16x8* bpf = reinterpret_cast<const s16x8*>(W1t + (size_t)col * 768);
#pragma unroll
  for (int kt = 0; kt < 24; ++kt) bfr[kt] = bpf[kt * 4 + quad];

  const f32x4* ap = reinterpret_cast<const f32x4*>(A + (size_t)rowbase * 768);
#pragma unroll
  for (int i = 0; i < 12; ++i) {
    const int ci = tid + 256 * i;
    f32x4 v = ap[ci];
    const int row = ci / 192, c4 = (ci % 192) * 4;
    s16x4 b; b[0] = f2bf(v[0]); b[1] = f2bf(v[1]); b[2] = f2bf(v[2]); b[3] = f2bf(v[3]);
    *reinterpret_cast<s16x4*>(&as16[row][c4]) = b;
  }
  __syncthreads();

  f32x4 acc = {0.f, 0.f, 0.f, 0.f};
#pragma unroll
  for (int kt = 0; kt < 24; ++kt) {
    s16x8 af = *reinterpret_cast<const s16x8*>(&as16[l15][kt * 32 + quad * 8]);
    acc = __builtin_amdgcn_mfma_f32_16x16x32_bf16(af, bfr[kt], acc, 0, 0, 0);
  }
  const float bn = b1[col];
#pragma unroll
  for (int r = 0; r < 4; ++r) {
    const int row = rowbase + quad * 4 + r;
    const float v = acc[r] + bn;
    H[(size_t)row * 512 + col] = v / (1.f + __expf(-v));
  }
}

__global__ __launch_bounds__(256) void k_mlp2(
    const float* __restrict__ A, const unsigned short* __restrict__ W2t,
    const float* __restrict__ b2, float* __restrict__ out) {
  __shared__ __align__(16) short as16[16][520];
  const int tid = threadIdx.x, lane = tid & 63, w = tid >> 6;
  const int quad = lane >> 4, l15 = lane & 15;
  const int rowbase = blockIdx.x * 16;
  const int col = blockIdx.y * 64 + w * 16 + l15;

  s16x8 bfr[16];
  const s16x8* bpf = reinterpret_cast<const s16x8*>(W2t + (size_t)col * 512);
#pragma unroll
  for (int kt = 0; kt < 16; ++kt) bfr[kt] = bpf[kt * 4 + quad];

  const f32x4* ap = reinterpret_cast<const f32x4*>(A + (size_t)rowbase * 512);
#pragma unroll
  for (int i = 0; i < 8; ++i) {
    const int ci = tid + 256 * i;
    f32x4 v = ap[ci];
    const int row = ci >> 7, c4 = (ci & 127) * 4;
    s16x4 b; b[0] = f2bf(v[0]); b[1] = f2bf(v[1]); b[2] = f2bf(v[2]); b[3] = f2bf(v[3]);
    *reinterpret_cast<s16x4*>(&as16[row][c4]) = b;
  }
  __syncthreads();

  f32x4 acc = {0.f, 0.f, 0.f, 0.f};
#pragma unroll
  for (int kt = 0; kt < 16; ++kt) {
    s16x8 af = *reinterpret_cast<const s16x8*>(&as16[l15][kt * 32 + quad * 8]);
    acc = __builtin_amdgcn_mfma_f32_16x16x32_bf16(af, bfr[kt], acc, 0, 0, 0);
  }
  const float bn = b2[col];
#pragma unroll
  for (int r = 0; r < 4; ++r) {
    const int row = rowbase + quad * 4 + r;
    out[(size_t)row * 256 + col] = acc[r] + bn;
  }
}

// ---------------------------------------------------------------------------
extern "C" void kernel_launch(void* const* d_in, const int* in_sizes, int n_in,
                              void* d_out, int out_size, void* d_ws, size_t ws_size,
                              hipStream_t stream) {
  const float* x    = (const float*)d_in[0];
  const int*   batch= (const int*)  d_in[1];
  const int*   mask = (const int*)  d_in[2];
  const float* aw1  = (const float*)d_in[4];
  const float* ab1  = (const float*)d_in[5];
  const float* aw2  = (const float*)d_in[6];
  const float* ab2  = (const float*)d_in[7];
  const float* we   = (const float*)d_in[8];
  const float* be   = (const float*)d_in[9];
  const float* wv   = (const float*)d_in[10];
  const float* bv   = (const float*)d_in[11];
  const float* wp   = (const float*)d_in[12];
  const float* bp   = (const float*)d_in[13];
  const float* w1   = (const float*)d_in[14];
  const float* b1   = (const float*)d_in[15];
  const float* w2   = (const float*)d_in[16];
  const float* b2   = (const float*)d_in[17];
  float* out = (float*)d_out;
  const int nn = in_sizes[1];   // 200000 nodes

  float* ws = (float*)d_ws;
  float* P    = ws;                         // 1024*768
  float* EXs  = P    + 786432;              // 1024*256
  float* ZCs  = EXs  + 262144;              // 1024*4 [z,c0,c1,c2]
  float* comb = ZCs  + 4096;                // 1024*768
  float* hbuf = comb + 786432;              // 1024*512
  unsigned short* Awt = (unsigned short*)(hbuf + 524288);   // 128*256
  unsigned short* Wpt = Awt + 32768;        // 256*768
  unsigned short* W1t = Wpt + 196608;       // 512*768
  unsigned short* W2t = W1t + 393216;       // 256*512

  hipMemsetAsync(P, 0, (size_t)(786432 + 262144 + 4096) * sizeof(float), stream);

  k_cvtw      <<<2944, 256, 0, stream>>>(aw1, we, wv, wp, w1, w2, Awt, Wpt, W1t, W2t);
  k_score_pool<<<1024, 256, 0, stream>>>(x, batch, mask, Awt, ab1, aw2, ab2, P, EXs, ZCs, nn);
  k_finalize  <<<1024, 256, 0, stream>>>(P, EXs, ZCs, comb);
  k_phys      <<<dim3(64, 4), 256, 0, stream>>>(P, Wpt, be, bv, bp, ZCs, comb);
  k_mlp1      <<<dim3(64, 8), 256, 0, stream>>>(comb, W1t, b1, hbuf);
  k_mlp2      <<<dim3(64, 4), 256, 0, stream>>>(hbuf, W2t, b2, out);
}